// Round 21
// baseline (32.982 us; speedup 1.0000x reference)
//
#include <hip/hip_runtime.h>
#include <math.h>

#define LQ 256
#define MEML 256
#define LK 512
#define BB 4
#define NH 8
#define DM 128

#define IT 8                  // i-tile per score block (20 KB LDS)
#define QSTRIDE 20            // LDS q row stride (floats)

constexpr float INV2PI = 0.15915494309189535f;

// ---------------------------------------------------------------------------
// Projection, 2 rows/block -> 1536 blocks (3 waves/SIMD; R20 had 0.75 and
// was latency-bound with nothing to overlap). Layouts identical to R12/R13:
//   qs[(i*4+b)*128 + h*16+d]
//   ksT[((d>>2)*512 + j)*128 + (b*8+h)*4 + (d&3)]
// ---------------------------------------------------------------------------
__global__ __launch_bounds__(128) void proj_kernel(
    const float* __restrict__ hh, const float* __restrict__ mems,
    const float* __restrict__ Wq, const float* __restrict__ Wk,
    const float* __restrict__ paramR,
    float* __restrict__ qs, float* __restrict__ ksT)
{
    __shared__ float x[2 * 128];
    const int blk = blockIdx.x;
    const int t = threadIdx.x;
    const bool isQ = (blk < 512);                 // 512 q-blocks, 1024 k-blocks
    const int row0 = isQ ? blk * 2 : (blk - 512) * 2;
    const float* __restrict__ W = isQ ? Wq : Wk;

    #pragma unroll
    for (int r = 0; r < 2; ++r) {
        const int row = row0 + r;
        const float* src = isQ ? (hh + row * DM)
                               : ((row < MEML * BB) ? (mems + row * DM)
                                                    : (hh + (row - MEML * BB) * DM));
        x[r * 128 + t] = src[t];
    }
    __syncthreads();

    float acc0 = 0.f, acc1 = 0.f;
    const float* wrow = W + t * DM;
    #pragma unroll 8
    for (int k = 0; k < DM; k += 4) {
        const float4 w  = *(const float4*)(wrow + k);
        const float4 x0 = *(const float4*)(&x[k]);
        const float4 x1 = *(const float4*)(&x[128 + k]);
        acc0 += x0.x * w.x + x0.y * w.y + x0.z * w.z + x0.w * w.w;
        acc1 += x1.x * w.x + x1.y * w.y + x1.z * w.z + x1.w * w.w;
    }
    const int h = t >> 4, d = t & 15;
    const float rs = paramR[h] * INV2PI;
    const float v0 = acc0 * rs, v1 = acc1 * rs;
    if (isQ) {
        qs[(row0 + 0) * 128 + t] = v0;
        qs[(row0 + 1) * 128 + t] = v1;
    } else {
        const int j0 = (row0 + 0) >> 2, b0 = (row0 + 0) & 3;
        const int j1 = (row0 + 1) >> 2, b1 = (row0 + 1) & 3;
        ksT[((d >> 2) * LK + j0) * 128 + (b0 * 8 + h) * 4 + (d & 3)] = v0;
        ksT[((d >> 2) * LK + j1) * 128 + (b1 * 8 + h) * 4 + (d & 3)] = v1;
    }
}

// ---------------------------------------------------------------------------
// Score (R13 verbatim — best measured, 29.75): 512 threads = (jj = t>>5,
// bh = t&31); IT=8 q-tile in LDS (swizzled chunk reads); k[16] in VGPRs.
// ---------------------------------------------------------------------------
__global__ __launch_bounds__(512, 2) void score_kernel(
    const float* __restrict__ qs, const float* __restrict__ ksT,
    float* __restrict__ out)
{
    __shared__ float qt[IT * 32 * QSTRIDE];       // 20480 B
    const int t = threadIdx.x;
    const int bh = t & 31;
    const int jj = t >> 5;                        // 0..15
    const int key = bh >> 3;                      // 0..3 chunk-permutation key
    const int i0 = blockIdx.x * IT;               // 32 i-tiles
    const int j = blockIdx.y * 16 + jj;           // 32 j-tiles of 16

    constexpr float i2 = INV2PI * INV2PI;
    constexpr float i4 = i2 * i2;
    constexpr float i8 = i4 * i4;
    constexpr float C16 = i8 * i8;                // (2pi)^-16
    constexpr float EPS = 2.0e-4f * INV2PI;       // 3.18e-5 rev; EPS^8 > FLT_MIN

    {
        const float* src = qs + i0 * 32 * 16;
        #pragma unroll
        for (int rep = 0; rep < 2; ++rep) {
            const int c4 = rep * 512 + t;         // float4 chunk id, 0..1023
            const int row = c4 >> 2, cc = (c4 & 3) * 4;
            const float4 v = *(const float4*)(src + c4 * 4);
            *(float4*)(&qt[row * QSTRIDE + cc]) = v;
        }
    }

    float k[16];
    #pragma unroll
    for (int s = 0; s < 4; ++s) {
        const int plane = s ^ key;
        const float4 v = *(const float4*)(ksT + (plane * LK + j) * 128 + bh * 4);
        k[s * 4 + 0] = v.x; k[s * 4 + 1] = v.y;
        k[s * 4 + 2] = v.z; k[s * 4 + 3] = v.w;
    }
    __syncthreads();

    #pragma unroll 4
    for (int ii = 0; ii < IT; ++ii) {
        const float* qrow = &qt[(ii * 32 + bh) * QSTRIDE];
        float q[16];
        #pragma unroll
        for (int s = 0; s < 4; ++s) {
            const float4 v = *(const float4*)(qrow + ((s ^ key) << 2));
            q[s * 4 + 0] = v.x; q[s * 4 + 1] = v.y;
            q[s * 4 + 2] = v.z; q[s * 4 + 3] = v.w;
        }
        float pn0 = 1.f, pd0 = 1.f, pn1 = 1.f, pd1 = 1.f;
        #pragma unroll
        for (int d = 0; d < 16; ++d) {
            const float u2 = fmaxf(__builtin_fabsf(q[d] - k[d]), EPS);
            const float s = __builtin_amdgcn_sinf(u2);   // sin(2pi*u2)
            if (d < 8) { pn0 *= s; pd0 *= u2; }
            else       { pn1 *= s; pd1 *= u2; }
        }
        const float r0 = pn0 * __builtin_amdgcn_rcpf(pd0);
        const float r1 = pn1 * __builtin_amdgcn_rcpf(pd1);
        out[((i0 + ii) * LK + j) * 32 + bh] = __builtin_fabsf(r0 * r1) * C16;
    }
}

extern "C" void kernel_launch(void* const* d_in, const int* in_sizes, int n_in,
                              void* d_out, int out_size, void* d_ws, size_t ws_size,
                              hipStream_t stream) {
    const float* hh     = (const float*)d_in[0];
    const float* mems   = (const float*)d_in[1];
    const float* Wq     = (const float*)d_in[2];
    const float* Wk     = (const float*)d_in[3];
    const float* paramR = (const float*)d_in[4];
    float* out = (float*)d_out;

    float* qs  = (float*)d_ws;                // 131072 floats
    float* ksT = qs + LQ * BB * DM;           // 262144 floats

    proj_kernel<<<1536, 128, 0, stream>>>(hh, mems, Wq, Wk, paramR, qs, ksT);
    score_kernel<<<dim3(LQ / IT, LK / 16), 512, 0, stream>>>(qs, ksT, out);
}